// Round 7
// baseline (590.989 us; speedup 1.0000x reference)
//
#include <hip/hip_runtime.h>

// GaussianSoftmax: out[b,n,m] = softmax_m( exp( exp(-max(||x_n-x_m||^2,0)/sigma) ) )
// X: [8, 4096, 16] fp32, sigma: [1], out: [8, 4096, 4096] fp32 (512 MiB).
//
// R18: overlap rewrite. Evidence R13-R17: all variants ~555-607 us; model
// that fits all five: store phase ~165us (3.1 TB/s) + compute 35-65us,
// SERIALIZED per block; every MFMA variant had 128 KiB LDS -> 1 block/CU ->
// zero compute/store overlap per CU. Fix: e lives packed-bf16 in VGPRs
// (64 u32/wave, compile-time indexed), LDS shrinks to one 33 KiB chunk
// buffer -> 2 blocks/CU (launch_bounds(512,4), VGPR<=128) -> block A
// computes while block B stores. Store phase per 1024-m chunk:
// VGPR->LDS (uint2, no VALU) -> barrier -> monotone contiguous 1 KiB/instr
// PLAIN stores (fill kernel's 6.2 TB/s uses cached writes; R16's plain
// penalty was serial-regime-confounded). Compute math bit-identical to
// R17 (harness-verified absmax 1.907e-6).

typedef float v4f __attribute__((ext_vector_type(4)));
typedef short bf8 __attribute__((ext_vector_type(8)));

constexpr int Bn  = 8;
constexpr int N   = 4096;
constexpr int F   = 16;
constexpr int BM  = 16;             // softmax rows per block (MFMA tile n)
constexpr int BLK = 512;            // 8 waves
constexpr int NW  = BLK / 64;       // 8
constexpr int NCH = 4;              // m-chunks of 1024
constexpr int TPC = 8;              // tile-pairs per wave per chunk
constexpr int ROWC = 1024 * 2 + 8;  // 2056 B padded LDS chunk-row stride

__device__ __forceinline__ unsigned short f2bf(float x) {   // RNE
    unsigned int u = __float_as_uint(x);
    unsigned int r = (u + 0x7FFFu + ((u >> 16) & 1u)) >> 16;
    return (unsigned short)r;
}
__device__ __forceinline__ float bf2f(unsigned short h) {
    return __uint_as_float(((unsigned int)h) << 16);
}
__device__ __forceinline__ float uni(float x) {
    return __int_as_float(__builtin_amdgcn_readfirstlane(__float_as_int(x)));
}

__global__ __launch_bounds__(256)
void pack_kernel(const float* __restrict__ X, uint4* __restrict__ Xp,
                 float* __restrict__ sqm) {
    const int b = blockIdx.y;
    const int m = blockIdx.x * 256 + threadIdx.x;
    const float4* src = (const float4*)(X + ((size_t)b * N + m) * F);
    const float4 v0 = src[0], v1 = src[1], v2 = src[2], v3 = src[3];
    const float x[F] = {v0.x, v0.y, v0.z, v0.w, v1.x, v1.y, v1.z, v1.w,
                        v2.x, v2.y, v2.z, v2.w, v3.x, v3.y, v3.z, v3.w};
    float s = 0.f;
    #pragma unroll
    for (int f = 0; f < F; ++f) s = fmaf(x[f], x[f], s);
    sqm[(size_t)b * N + m] = s;

    uint4* dst = Xp + ((size_t)b * N + m) * 4;
    #pragma unroll
    for (int g = 0; g < 4; ++g) {
        unsigned int hi[4], lo[4];
        #pragma unroll
        for (int j = 0; j < 4; ++j) {
            const float xf = x[4 * g + j];
            const unsigned short h = f2bf(xf);
            hi[j] = h;
            lo[j] = f2bf(xf - bf2f(h));
        }
        uint4 c;
        c.x = hi[0] | (hi[1] << 16);
        c.y = hi[2] | (hi[3] << 16);
        c.z = lo[0] | (lo[1] << 16);
        c.w = lo[2] | (lo[3] << 16);
        dst[g] = c;
    }
}

union BfU { uint4 u; bf8 h; };

__global__ __launch_bounds__(BLK, 4)
void gs_mfma(const uint4* __restrict__ Xp, const float* __restrict__ sqm,
             const float* __restrict__ sigma_p, float* __restrict__ out) {
    extern __shared__ char smem[];
    float* red   = (float*)(smem + (size_t)BM * ROWC);   // NW x BM partials
    float* inv16 = red + NW * BM;                        // 16 row inverses

    const int tid  = threadIdx.x;
    const int w    = tid >> 6;
    const int lane = tid & 63;
    const int g    = lane >> 4;
    const int cc   = lane & 15;
    const int b    = blockIdx.y;
    const int n0   = blockIdx.x * BM;

    const uint4* Xpb = Xp + (size_t)b * N * 4;
    const float* sqb = sqm + (size_t)b * N;

    // Block-constant B frags (n-side rows n0..n0+15), hi/lo and swapped.
    BfU b1; b1.u = Xpb[(size_t)(n0 + cc) * 4 + g];
    BfU b2; b2.u = make_uint4(b1.u.z, b1.u.w, b1.u.x, b1.u.y);

    const float sqn_l = sqb[n0 + cc];
    const float nis   = uni(-1.0f / sigma_p[0]);

    unsigned int e_pk[NCH * TPC * 2];   // packed bf16 e, 64 VGPR, static-indexed
    float psum = 0.f;

    // Pass 1: compute all tiles, e stays in registers (packed bf16).
    #pragma unroll
    for (int c = 0; c < NCH; ++c) {
        #pragma unroll
        for (int t = 0; t < TPC; ++t) {
            const int m_tile = (c * 64 + w * TPC + t) * 16;
            BfU a; a.u = Xpb[(size_t)(m_tile + cc) * 4 + g];

            v4f acc = {0.f, 0.f, 0.f, 0.f};
            acc = __builtin_amdgcn_mfma_f32_16x16x32_bf16(a.h, b1.h, acc, 0, 0, 0);
            acc = __builtin_amdgcn_mfma_f32_16x16x32_bf16(a.h, b2.h, acc, 0, 0, 0);
            // acc[j] = inner(x_{m_tile+4g+j}, x_{n0+cc})

            const v4f sm4 = *(const v4f*)(sqb + m_tile + 4 * g);
            float ex = __expf(__expf(fmaxf(fmaf(-2.f, acc.x, sqn_l + sm4.x), 0.f) * nis));
            float ey = __expf(__expf(fmaxf(fmaf(-2.f, acc.y, sqn_l + sm4.y), 0.f) * nis));
            float ez = __expf(__expf(fmaxf(fmaf(-2.f, acc.z, sqn_l + sm4.z), 0.f) * nis));
            float ew = __expf(__expf(fmaxf(fmaf(-2.f, acc.w, sqn_l + sm4.w), 0.f) * nis));

            e_pk[(c * TPC + t) * 2 + 0] = (unsigned int)f2bf(ex) | ((unsigned int)f2bf(ey) << 16);
            e_pk[(c * TPC + t) * 2 + 1] = (unsigned int)f2bf(ez) | ((unsigned int)f2bf(ew) << 16);
            psum += (ex + ey) + (ez + ew);
        }
    }

    // Row sums: fold g-groups (lane&15 = row), then cross-wave.
    psum += __shfl_xor(psum, 16, 64);
    psum += __shfl_xor(psum, 32, 64);
    if (lane < 16) red[w * BM + lane] = psum;
    __syncthreads();
    if (w == 0 && lane < 16) {
        float tot = 0.f;
        #pragma unroll
        for (int w2 = 0; w2 < NW; ++w2) tot += red[w2 * BM + lane];
        inv16[lane] = 1.0f / tot;
    }
    __syncthreads();

    // Pass 2: per 1024-m chunk: VGPR -> LDS -> contiguous stores.
    #pragma unroll
    for (int c = 0; c < NCH; ++c) {
        #pragma unroll
        for (int t = 0; t < TPC; ++t) {
            const int gl = (w * TPC + t) * 4 + g;   // 8B granule in chunk-row
            uint2 pk;
            pk.x = e_pk[(c * TPC + t) * 2 + 0];
            pk.y = e_pk[(c * TPC + t) * 2 + 1];
            *(uint2*)(smem + (size_t)cc * ROWC + 8 * gl) = pk;   // ~4-way max
        }
        __syncthreads();

        #pragma unroll
        for (int rsel = 0; rsel < 2; ++rsel) {
            const int rr = w + rsel * NW;
            const float invr = inv16[rr];            // wave-uniform broadcast
            float* rowp = out + ((size_t)b * N + n0 + rr) * (size_t)N + c * 1024;
            #pragma unroll
            for (int k = 0; k < 4; ++k) {
                const int gp = 64 * k + lane;        // float4 index in chunk
                const uint2 pk = *(const uint2*)(smem + (size_t)rr * ROWC + 8 * gp);
                v4f v;
                v.x = __uint_as_float(pk.x << 16) * invr;
                v.y = __uint_as_float(pk.x & 0xffff0000u) * invr;
                v.z = __uint_as_float(pk.y << 16) * invr;
                v.w = __uint_as_float(pk.y & 0xffff0000u) * invr;
                ((v4f*)rowp)[gp] = v;                // monotone 1 KiB/instr
            }
        }
        __syncthreads();   // before next chunk overwrites the buffer
    }
}

extern "C" void kernel_launch(void* const* d_in, const int* in_sizes, int n_in,
                              void* d_out, int out_size, void* d_ws, size_t ws_size,
                              hipStream_t stream) {
    const float* X     = (const float*)d_in[0];
    const float* sigma = (const float*)d_in[1];
    float* out         = (float*)d_out;
    uint4* Xp          = (uint4*)d_ws;                              // 2 MiB
    float* sqm         = (float*)d_ws + (size_t)Bn * N * 16;        // +128 KiB

    const size_t lds_bytes = (size_t)BM * ROWC + NW * BM * 4 + 16 * 4;  // ~33 KiB
    pack_kernel<<<dim3(N / 256, Bn), 256, 0, stream>>>(X, Xp, sqm);
    gs_mfma<<<dim3(N / BM, Bn), BLK, lds_bytes, stream>>>(Xp, sqm, sigma, out);
}

// Round 8
// 536.114 us; speedup vs baseline: 1.1024x; 1.1024x over previous
//
#include <hip/hip_runtime.h>

// GaussianSoftmax: out[b,n,m] = softmax_m( exp( exp(-max(||x_n-x_m||^2,0)/sigma) ) )
// X: [8, 4096, 16] fp32, sigma: [1], out: [8, 4096, 4096] fp32 (512 MiB).
//
// R19: 2-blocks/CU overlap with the PROVEN R17 store pattern.
// Budget correction (R7 post-mortem): timed window = 342us ws-fill + ~85us
// out-fill (both harness) + ~20us resets/pack + gs. R13/R15/R17 => gs ~110us
// vs 85-90us write floor; residual = compute serialization at 1 block/CU
// (128 KiB LDS). Fix: stage e bf16 for cols 0..2047 in LDS (64 KiB, padded
// stride 4104B), keep cols 2048..4095 packed bf16 in VGPRs (32 u32/lane,
// 8-wave block, <=128 VGPR) -> 2 blocks/CU, compute of block A overlaps
// store of block B. Store phase: chunk A from LDS (monotone contiguous 1KiB
// nt dwordx4, R17-proven), barrier, VGPR->LDS (R18-proven granule map),
// barrier, chunk B. Math bit-identical to R17 (absmax 1.907e-6 expected).

typedef float v4f __attribute__((ext_vector_type(4)));
typedef short bf8 __attribute__((ext_vector_type(8)));

constexpr int Bn  = 8;
constexpr int N   = 4096;
constexpr int F   = 16;
constexpr int BM  = 16;             // softmax rows per block (MFMA tile n)
constexpr int BLK = 512;            // 8 waves
constexpr int NW  = BLK / 64;       // 8
constexpr int ROWC = 2048 * 2 + 8;  // 4104 B padded LDS chunk-row stride

__device__ __forceinline__ unsigned short f2bf(float x) {   // RNE
    unsigned int u = __float_as_uint(x);
    unsigned int r = (u + 0x7FFFu + ((u >> 16) & 1u)) >> 16;
    return (unsigned short)r;
}
__device__ __forceinline__ float bf2f(unsigned short h) {
    return __uint_as_float(((unsigned int)h) << 16);
}
__device__ __forceinline__ float uni(float x) {
    return __int_as_float(__builtin_amdgcn_readfirstlane(__float_as_int(x)));
}

__global__ __launch_bounds__(256)
void pack_kernel(const float* __restrict__ X, uint4* __restrict__ Xp,
                 float* __restrict__ sqm) {
    const int b = blockIdx.y;
    const int m = blockIdx.x * 256 + threadIdx.x;
    const float4* src = (const float4*)(X + ((size_t)b * N + m) * F);
    const float4 v0 = src[0], v1 = src[1], v2 = src[2], v3 = src[3];
    const float x[F] = {v0.x, v0.y, v0.z, v0.w, v1.x, v1.y, v1.z, v1.w,
                        v2.x, v2.y, v2.z, v2.w, v3.x, v3.y, v3.z, v3.w};
    float s = 0.f;
    #pragma unroll
    for (int f = 0; f < F; ++f) s = fmaf(x[f], x[f], s);
    sqm[(size_t)b * N + m] = s;

    uint4* dst = Xp + ((size_t)b * N + m) * 4;
    #pragma unroll
    for (int g = 0; g < 4; ++g) {
        unsigned int hi[4], lo[4];
        #pragma unroll
        for (int j = 0; j < 4; ++j) {
            const float xf = x[4 * g + j];
            const unsigned short h = f2bf(xf);
            hi[j] = h;
            lo[j] = f2bf(xf - bf2f(h));
        }
        uint4 c;
        c.x = hi[0] | (hi[1] << 16);
        c.y = hi[2] | (hi[3] << 16);
        c.z = lo[0] | (lo[1] << 16);
        c.w = lo[2] | (lo[3] << 16);
        dst[g] = c;
    }
}

union BfU { uint4 u; bf8 h; };

__global__ __launch_bounds__(BLK, 4)
void gs_mfma(const uint4* __restrict__ Xp, const float* __restrict__ sqm,
             const float* __restrict__ sigma_p, float* __restrict__ out) {
    extern __shared__ char smem[];
    float* red   = (float*)(smem + (size_t)BM * ROWC);   // NW x BM partials
    float* inv16 = red + NW * BM;                        // 16 row inverses

    const int tid  = threadIdx.x;
    const int w    = tid >> 6;
    const int lane = tid & 63;
    const int g    = lane >> 4;
    const int cc   = lane & 15;
    const int b    = blockIdx.y;
    const int n0   = blockIdx.x * BM;

    const uint4* Xpb = Xp + (size_t)b * N * 4;
    const float* sqb = sqm + (size_t)b * N;

    // Block-constant B frags (n-side rows n0..n0+15), hi/lo and swapped.
    BfU b1; b1.u = Xpb[(size_t)(n0 + cc) * 4 + g];
    BfU b2; b2.u = make_uint4(b1.u.z, b1.u.w, b1.u.x, b1.u.y);

    const float sqn_l = sqb[n0 + cc];
    const float nis   = uni(-1.0f / sigma_p[0]);

    unsigned int e_pk[32];   // cols 2048..4095: 16 tiles x 2 u32, static-indexed
    float psum = 0.f;

    // Pass 1a: cols 0..2047 -> LDS (wave-interleaved tiles: m_tile=(t*8+w)*16).
    #pragma unroll
    for (int t = 0; t < 16; ++t) {
        const int m_tile = (t * 8 + w) * 16;
        BfU a; a.u = Xpb[(size_t)(m_tile + cc) * 4 + g];

        v4f acc = {0.f, 0.f, 0.f, 0.f};
        acc = __builtin_amdgcn_mfma_f32_16x16x32_bf16(a.h, b1.h, acc, 0, 0, 0);
        acc = __builtin_amdgcn_mfma_f32_16x16x32_bf16(a.h, b2.h, acc, 0, 0, 0);

        const v4f sm4 = *(const v4f*)(sqb + m_tile + 4 * g);
        float ex = __expf(__expf(fmaxf(fmaf(-2.f, acc.x, sqn_l + sm4.x), 0.f) * nis));
        float ey = __expf(__expf(fmaxf(fmaf(-2.f, acc.y, sqn_l + sm4.y), 0.f) * nis));
        float ez = __expf(__expf(fmaxf(fmaf(-2.f, acc.z, sqn_l + sm4.z), 0.f) * nis));
        float ew = __expf(__expf(fmaxf(fmaf(-2.f, acc.w, sqn_l + sm4.w), 0.f) * nis));

        uint2 pk;
        pk.x = (unsigned int)f2bf(ex) | ((unsigned int)f2bf(ey) << 16);
        pk.y = (unsigned int)f2bf(ez) | ((unsigned int)f2bf(ew) << 16);
        const int gl = (t * 8 + w) * 4 + g;          // 8B granule, 0..511
        *(uint2*)(smem + (size_t)cc * ROWC + 8 * gl) = pk;   // ~4-way max

        psum += (ex + ey) + (ez + ew);
    }

    // Pass 1b: cols 2048..4095 -> VGPRs.
    #pragma unroll
    for (int t = 0; t < 16; ++t) {
        const int m_tile = 2048 + (t * 8 + w) * 16;
        BfU a; a.u = Xpb[(size_t)(m_tile + cc) * 4 + g];

        v4f acc = {0.f, 0.f, 0.f, 0.f};
        acc = __builtin_amdgcn_mfma_f32_16x16x32_bf16(a.h, b1.h, acc, 0, 0, 0);
        acc = __builtin_amdgcn_mfma_f32_16x16x32_bf16(a.h, b2.h, acc, 0, 0, 0);

        const v4f sm4 = *(const v4f*)(sqb + m_tile + 4 * g);
        float ex = __expf(__expf(fmaxf(fmaf(-2.f, acc.x, sqn_l + sm4.x), 0.f) * nis));
        float ey = __expf(__expf(fmaxf(fmaf(-2.f, acc.y, sqn_l + sm4.y), 0.f) * nis));
        float ez = __expf(__expf(fmaxf(fmaf(-2.f, acc.z, sqn_l + sm4.z), 0.f) * nis));
        float ew = __expf(__expf(fmaxf(fmaf(-2.f, acc.w, sqn_l + sm4.w), 0.f) * nis));

        e_pk[t * 2 + 0] = (unsigned int)f2bf(ex) | ((unsigned int)f2bf(ey) << 16);
        e_pk[t * 2 + 1] = (unsigned int)f2bf(ez) | ((unsigned int)f2bf(ew) << 16);
        psum += (ex + ey) + (ez + ew);
    }

    // Row sums: fold g-groups (lane&15 = row), then cross-wave.
    psum += __shfl_xor(psum, 16, 64);
    psum += __shfl_xor(psum, 32, 64);
    if (lane < 16) red[w * BM + lane] = psum;
    __syncthreads();   // red + chunk-A lds_e visible
    if (w == 0 && lane < 16) {
        float tot = 0.f;
        #pragma unroll
        for (int w2 = 0; w2 < NW; ++w2) tot += red[w2 * BM + lane];
        inv16[lane] = 1.0f / tot;
    }
    __syncthreads();

    // Store chunk A (cols 0..2047): wave w -> rows w and w+8, monotone
    // contiguous 1 KiB nt stores (R17-proven pattern).
    #pragma unroll
    for (int rsel = 0; rsel < 2; ++rsel) {
        const int r = w + rsel * NW;
        const float invr = uni(inv16[r]);
        float* rowp = out + ((size_t)b * N + n0 + r) * (size_t)N;
        #pragma unroll
        for (int k = 0; k < 8; ++k) {
            const int gp = 64 * k + lane;
            const uint2 pk = *(const uint2*)(smem + (size_t)r * ROWC + 8 * gp);
            v4f v;
            v.x = __uint_as_float(pk.x << 16) * invr;
            v.y = __uint_as_float(pk.x & 0xffff0000u) * invr;
            v.z = __uint_as_float(pk.y << 16) * invr;
            v.w = __uint_as_float(pk.y & 0xffff0000u) * invr;
            __builtin_nontemporal_store(v, (v4f*)rowp + gp);
        }
    }
    __syncthreads();   // chunk-A reads done before overwrite

    // VGPR -> LDS for chunk B (same granule map as pass 1a).
    #pragma unroll
    for (int t = 0; t < 16; ++t) {
        const int gl = (t * 8 + w) * 4 + g;
        uint2 pk;
        pk.x = e_pk[t * 2 + 0];
        pk.y = e_pk[t * 2 + 1];
        *(uint2*)(smem + (size_t)cc * ROWC + 8 * gl) = pk;
    }
    __syncthreads();

    // Store chunk B (cols 2048..4095).
    #pragma unroll
    for (int rsel = 0; rsel < 2; ++rsel) {
        const int r = w + rsel * NW;
        const float invr = uni(inv16[r]);
        float* rowp = out + ((size_t)b * N + n0 + r) * (size_t)N + 2048;
        #pragma unroll
        for (int k = 0; k < 8; ++k) {
            const int gp = 64 * k + lane;
            const uint2 pk = *(const uint2*)(smem + (size_t)r * ROWC + 8 * gp);
            v4f v;
            v.x = __uint_as_float(pk.x << 16) * invr;
            v.y = __uint_as_float(pk.x & 0xffff0000u) * invr;
            v.z = __uint_as_float(pk.y << 16) * invr;
            v.w = __uint_as_float(pk.y & 0xffff0000u) * invr;
            __builtin_nontemporal_store(v, (v4f*)rowp + gp);
        }
    }
}

extern "C" void kernel_launch(void* const* d_in, const int* in_sizes, int n_in,
                              void* d_out, int out_size, void* d_ws, size_t ws_size,
                              hipStream_t stream) {
    const float* X     = (const float*)d_in[0];
    const float* sigma = (const float*)d_in[1];
    float* out         = (float*)d_out;
    uint4* Xp          = (uint4*)d_ws;                              // 2 MiB
    float* sqm         = (float*)d_ws + (size_t)Bn * N * 16;        // +128 KiB

    const size_t lds_bytes = (size_t)BM * ROWC + NW * BM * 4 + 16 * 4;  // ~64.7 KiB
    pack_kernel<<<dim3(N / 256, Bn), 256, 0, stream>>>(X, Xp, sqm);
    gs_mfma<<<dim3(N / BM, Bn), BLK, lds_bytes, stream>>>(Xp, sqm, sigma, out);
}